// Round 3
// baseline (185.674 us; speedup 1.0000x reference)
//
#include <hip/hip_runtime.h>
#include <hip/hip_bf16.h>

typedef __attribute__((ext_vector_type(8))) short short8;
typedef __attribute__((ext_vector_type(4))) float f32x4;

#define NGRAPHS 1024
#define D_DIM 512
#define H_DIM 128

#define BM 128
#define BK 64
#define LDK 72  // padded LDS row stride in bf16 elements (144 B -> 2-way bank alias, free)

static __device__ __forceinline__ unsigned short f2bf(float f) {
    union { float f; unsigned int u; } v;
    v.f = f;
    unsigned int u = v.u;
    // round-to-nearest-even bf16
    unsigned int r = (u + 0x7FFFu + ((u >> 16) & 1u)) >> 16;
    return (unsigned short)r;
}

static __device__ __forceinline__ float fast_tanh(float x) {
    float cx = fminf(fmaxf(x, -15.f), 15.f);
    float e = __expf(2.f * cx);
    return (e - 1.f) / (e + 1.f);
}

// ---------------- Kernel 0: segment offsets via binary search ----------------
__global__ void seg_offsets_kernel(const int* __restrict__ batch, int N,
                                   int* __restrict__ off) {
    int g = blockIdx.x * 256 + threadIdx.x;
    if (g > NGRAPHS) return;
    int lo = 0, hi = N;
    while (lo < hi) {
        int mid = (lo + hi) >> 1;
        if (batch[mid] < g) lo = mid + 1;
        else hi = mid;
    }
    off[g] = lo;
}

// ---------------- Kernel P: W1 [512][128] f32 -> W1T [128][512] bf16 ----------------
__global__ void prep_w1t_kernel(const float* __restrict__ W1,
                                unsigned short* __restrict__ W1T) {
    int idx = blockIdx.x * 256 + threadIdx.x;  // 0..65535
    int n = idx >> 9;        // 0..127
    int k = idx & 511;       // 0..511
    W1T[idx] = f2bf(W1[k * H_DIM + n]);
}

// ---------------- Kernel A: gate MLP -> logits ----------------
// grid = ceil(N/128), block = 256 (4 waves). Wave w owns rows [w*32, w*32+32).
__global__ __launch_bounds__(256) void gate_logits_kernel(
    const float* __restrict__ h, const unsigned short* __restrict__ W1T,
    const float* __restrict__ b1, const float* __restrict__ W2,
    const float* __restrict__ b2, float* __restrict__ logits, int Ntot) {
    __shared__ unsigned short sA[BM * LDK];     // h tile, bf16, [row][k]
    __shared__ unsigned short sB[H_DIM * LDK];  // W1T tile, bf16, [n][k]

    const int tid = threadIdx.x;
    const int lane = tid & 63;
    const int w = tid >> 6;
    const int row0 = blockIdx.x * BM;

    // epilogue constants: this lane's 8 columns (ni*16 + (lane&15))
    const int cg = lane & 15;
    float b1v[8], w2v[8];
#pragma unroll
    for (int ni = 0; ni < 8; ++ni) {
        b1v[ni] = b1[ni * 16 + cg];
        w2v[ni] = W2[ni * 16 + cg];
    }
    const float b2v = b2[0];

    f32x4 acc[2][8];
#pragma unroll
    for (int mi = 0; mi < 2; ++mi)
#pragma unroll
        for (int ni = 0; ni < 8; ++ni)
            acc[mi][ni] = (f32x4){0.f, 0.f, 0.f, 0.f};

    const int ar = tid >> 2;  // 0..63 (row within half-tile)
    const int aq = tid & 3;   // quarter of a 64-wide k-slice (16 floats)
    const int klo = (lane >> 4) * 8;

    for (int kk = 0; kk < D_DIM; kk += BK) {
        // ---- stage A: h[row0..row0+127][kk..kk+63] -> bf16 LDS ----
#pragma unroll
        for (int half = 0; half < 2; ++half) {
            const int r = ar + half * 64;
            const int grow = row0 + r;
            float4 f[4];
            if (grow < Ntot) {
                const float4* src =
                    (const float4*)(h + (size_t)grow * D_DIM + kk + aq * 16);
#pragma unroll
                for (int j = 0; j < 4; ++j) f[j] = src[j];
            } else {
#pragma unroll
                for (int j = 0; j < 4; ++j) f[j] = (float4){0.f, 0.f, 0.f, 0.f};
            }
            unsigned short* dst = &sA[r * LDK + aq * 16];
#pragma unroll
            for (int j = 0; j < 4; ++j) {
                ushort4 u;
                u.x = f2bf(f[j].x);
                u.y = f2bf(f[j].y);
                u.z = f2bf(f[j].z);
                u.w = f2bf(f[j].w);
                *(ushort4*)(dst + j * 4) = u;
            }
        }
        // ---- stage B: W1T[n][kk..kk+63] -> LDS (already bf16) ----
        {
            const int n = tid >> 1;
            const int halfk = tid & 1;
            const uint4* src =
                (const uint4*)(W1T + (size_t)n * D_DIM + kk + halfk * 32);
            uint4* dst = (uint4*)&sB[n * LDK + halfk * 32];
#pragma unroll
            for (int j = 0; j < 4; ++j) dst[j] = src[j];
        }
        __syncthreads();

        // ---- MFMA ----
#pragma unroll
        for (int ki = 0; ki < 2; ++ki) {
            short8 af[2];
            short8 bf[8];
#pragma unroll
            for (int mi = 0; mi < 2; ++mi)
                af[mi] = *(const short8*)&sA[(w * 32 + mi * 16 + (lane & 15)) * LDK +
                                             ki * 32 + klo];
#pragma unroll
            for (int ni = 0; ni < 8; ++ni)
                bf[ni] = *(const short8*)&sB[(ni * 16 + (lane & 15)) * LDK +
                                             ki * 32 + klo];
#pragma unroll
            for (int mi = 0; mi < 2; ++mi)
#pragma unroll
                for (int ni = 0; ni < 8; ++ni)
                    acc[mi][ni] = __builtin_amdgcn_mfma_f32_16x16x32_bf16(
                        af[mi], bf[ni], acc[mi][ni], 0, 0, 0);
        }
        __syncthreads();
    }

    // ---- epilogue: logit[row] = sum_col tanh(u + b1[col]) * W2[col] + b2 ----
    const int rgrp = lane >> 4;
#pragma unroll
    for (int mi = 0; mi < 2; ++mi) {
#pragma unroll
        for (int reg = 0; reg < 4; ++reg) {
            float p = 0.f;
#pragma unroll
            for (int ni = 0; ni < 8; ++ni) {
                float u = acc[mi][ni][reg] + b1v[ni];
                p += fast_tanh(u) * w2v[ni];
            }
#pragma unroll
            for (int o = 1; o < 16; o <<= 1) p += __shfl_xor(p, o, 64);
            const int row = row0 + w * 32 + mi * 16 + rgrp * 4 + reg;
            if ((lane & 15) == 0 && row < Ntot) logits[row] = p + b2v;
        }
    }
}

// ---------------- Kernel C: segment softmax + weighted pooling ----------------
// grid = 1024 (one block per graph), block = 512 (thread t owns output dim t)
__global__ __launch_bounds__(512) void pool_kernel(
    const float* __restrict__ h, const float* __restrict__ logits,
    const int* __restrict__ off, float* __restrict__ out) {
    const int g = blockIdx.x;
    const int tid = threadIdx.x;
    const int start = off[g];
    const int end = off[g + 1];
    const int n = end - start;

    __shared__ float red[8];
    __shared__ float wlds[1024];

    if (n <= 0) {
        out[(size_t)g * D_DIM + tid] = 0.f;
        return;
    }

    // pass 1: segment max
    float m = -3.0e38f;
    for (int i = start + tid; i < end; i += 512) m = fmaxf(m, logits[i]);
#pragma unroll
    for (int o = 1; o < 64; o <<= 1) m = fmaxf(m, __shfl_xor(m, o, 64));
    if ((tid & 63) == 0) red[tid >> 6] = m;
    __syncthreads();
    float bm = red[0];
#pragma unroll
    for (int j = 1; j < 8; ++j) bm = fmaxf(bm, red[j]);
    __syncthreads();

    // pass 2: denominator
    float s = 0.f;
    for (int i = start + tid; i < end; i += 512) s += __expf(logits[i] - bm);
#pragma unroll
    for (int o = 1; o < 64; o <<= 1) s += __shfl_xor(s, o, 64);
    if ((tid & 63) == 0) red[tid >> 6] = s;
    __syncthreads();
    float denom = 0.f;
#pragma unroll
    for (int j = 0; j < 8; ++j) denom += red[j];
    const float inv = 1.0f / denom;

    // pass 3: weighted accumulation, weights staged in LDS per chunk
    float acc = 0.f;
    for (int c0 = start; c0 < end; c0 += 1024) {
        const int cn = min(1024, end - c0);
        __syncthreads();
        for (int j = tid; j < cn; j += 512)
            wlds[j] = __expf(logits[c0 + j] - bm) * inv;
        __syncthreads();
        const float* hp = h + (size_t)c0 * D_DIM + tid;
#pragma unroll 4
        for (int j = 0; j < cn; ++j) {
            acc += wlds[j] * hp[0];
            hp += D_DIM;
        }
    }
    out[(size_t)g * D_DIM + tid] = acc;
}

extern "C" void kernel_launch(void* const* d_in, const int* in_sizes, int n_in,
                              void* d_out, int out_size, void* d_ws, size_t ws_size,
                              hipStream_t stream) {
    const float* h = (const float*)d_in[0];
    const int* batch = (const int*)d_in[1];
    const float* W1 = (const float*)d_in[2];
    const float* b1 = (const float*)d_in[3];
    const float* W2 = (const float*)d_in[4];
    const float* b2 = (const float*)d_in[5];
    float* out = (float*)d_out;
    const int N = in_sizes[1];  // number of nodes (batch length)

    char* ws = (char*)d_ws;
    int* off = (int*)ws;                                   // 1025 ints (4100 B)
    unsigned short* W1T = (unsigned short*)(ws + 4608);    // 131072 B
    float* logits = (float*)(ws + 4608 + 131072);          // N floats

    seg_offsets_kernel<<<(NGRAPHS + 256) / 256 + 1, 256, 0, stream>>>(batch, N, off);
    prep_w1t_kernel<<<(D_DIM * H_DIM) / 256, 256, 0, stream>>>(W1, W1T);
    gate_logits_kernel<<<(N + BM - 1) / BM, 256, 0, stream>>>(h, W1T, b1, W2, b2,
                                                              logits, N);
    pool_kernel<<<NGRAPHS, 512, 0, stream>>>(h, logits, off, out);
}